// Round 1
// baseline (214.929 us; speedup 1.0000x reference)
//
#include <hip/hip_runtime.h>

// SpatialNonIntersectionAxiom: B=8, N=512, E=4096.
// Outputs (flat f32): [0] = loss, [1 .. 1+E*E) = violation_mask (0/1),
// [1+E*E .. 1+2*E*E) = violation_scores (= pair_loss).

#define EDGES   4096
#define LOGE    12
#define EPS     0.001f
#define PROX    0.15f
#define NBUCKET 2048

__global__ __launch_bounds__(256) void pair_kernel(
    const float2* __restrict__ pos,       // 4096 nodes (B*N), xy
    const int*    __restrict__ esrc,      // edge_index[0], E ints
    const int*    __restrict__ edst,      // edge_index[1], E ints
    float*        __restrict__ out,       // d_out
    float*        __restrict__ bsum,      // NBUCKET partial sums (ws)
    unsigned int* __restrict__ bcnt)      // NBUCKET partial counts (ws)
{
#pragma clang fp contract(off)
    const int k = blockIdx.x * 256 + threadIdx.x;   // pair index, < E*E
    const int i = k >> LOGE;
    const int j = k & (EDGES - 1);

    const int si = esrc[i], di = edst[i];
    const int sj = esrc[j], dj = edst[j];
    const float2 a1 = pos[si], a2 = pos[di];
    const float2 b1 = pos[sj], b2 = pos[dj];

    // ---------- candidate mask (elementwise path, plain f32, no FMA) ----------
    const float d1ix = a2.x - a1.x, d1iy = a2.y - a1.y;
    const float d1jx = b2.x - b1.x, d1jy = b2.y - b1.y;
    const float midix = (a1.x + a2.x) * 0.5f, midiy = (a1.y + a2.y) * 0.5f;
    const float midjx = (b1.x + b2.x) * 0.5f, midjy = (b1.y + b2.y) * 0.5f;
    const float half_i = sqrtf(d1ix * d1ix + d1iy * d1iy) * 0.5f;
    const float half_j = sqrtf(d1jx * d1jx + d1jy * d1jy) * 0.5f;
    const float dmx = midix - midjx, dmy = midiy - midjy;
    const float dist  = sqrtf(dmx * dmx + dmy * dmy);
    const float reach = half_i + half_j + PROX;

    const bool upper  = j > i;
    const bool sameb  = (si >> 9) == (sj >> 9);           // batch = src // 512
    const bool shares = (si == sj) || (si == dj) || (di == sj) || (di == dj);
    const bool mask   = (dist < reach) && upper && sameb && !shares;

    // ---------- segment-segment distance (reference op order; dead t skipped) ----------
    const float sqi = fmaxf(d1ix * d1ix + d1iy * d1iy, 1e-12f);   // a
    const float sqj = fmaxf(d1jx * d1jx + d1jy * d1jy, 1e-12f);   // e
    const float b   = d1ix * d1jx + d1iy * d1jy;
    const float ddai = d1ix * a1.x + d1iy * a1.y;                 // d1_i . p_src_i
    const float ddaj = d1jx * b1.x + d1jy * b1.y;                 // d1_j . p_src_j
    const float c = ddai - (d1ix * b1.x + d1iy * b1.y);
    const float f = (a1.x * d1jx + a1.y * d1jy) - ddaj;
    const float denom = fmaxf(sqi * sqj - b * b, 1e-12f);

    float s = (b * f - c * sqj) / denom;
    s = fminf(fmaxf(s, 0.0f), 1.0f);
    const float t = fminf(fmaxf((b * s + f) / sqj, 0.0f), 1.0f);
    s = fminf(fmaxf((b * t - c) / sqi, 0.0f), 1.0f);

    const float cax = a1.x + s * d1ix, cay = a1.y + s * d1iy;
    const float cbx = b1.x + t * d1jx, cby = b1.y + t * d1jy;
    const float dx = cax - cbx, dy = cay - cby;
    const float dmin = sqrtf(dx * dx + dy * dy);

    const float mf = mask ? 1.0f : 0.0f;
    const float pl = fmaxf(EPS - dmin, 0.0f) * mf;

    out[1 + k] = (mask && pl > 0.0f) ? 1.0f : 0.0f;          // violation_mask
    out[1 + EDGES * EDGES + k] = pl;                          // violation_scores

    // ---------- reduction: pair_loss sum + mask count ----------
    float vsum = pl;
    int   vcnt = mask ? 1 : 0;
    #pragma unroll
    for (int off = 32; off > 0; off >>= 1) {
        vsum += __shfl_xor(vsum, off, 64);
        vcnt += __shfl_xor(vcnt, off, 64);
    }
    __shared__ float    ls[4];
    __shared__ unsigned lc[4];
    const int wid = threadIdx.x >> 6, lane = threadIdx.x & 63;
    if (lane == 0) { ls[wid] = vsum; lc[wid] = (unsigned)vcnt; }
    __syncthreads();
    if (threadIdx.x == 0) {
        const float    s4 = ls[0] + ls[1] + ls[2] + ls[3];
        const unsigned c4 = lc[0] + lc[1] + lc[2] + lc[3];
        const int bk = blockIdx.x & (NBUCKET - 1);
        atomicAdd(&bsum[bk], s4);
        atomicAdd(&bcnt[bk], c4);
    }
}

__global__ __launch_bounds__(256) void finalize_kernel(
    const float* __restrict__ bsum, const unsigned* __restrict__ bcnt,
    float* __restrict__ out)
{
    float    s = 0.0f;
    unsigned c = 0u;
    for (int b = threadIdx.x; b < NBUCKET; b += 256) { s += bsum[b]; c += bcnt[b]; }
    #pragma unroll
    for (int off = 32; off > 0; off >>= 1) {
        s += __shfl_xor(s, off, 64);
        c += (unsigned)__shfl_xor((int)c, off, 64);
    }
    __shared__ float    ls[4];
    __shared__ unsigned lc[4];
    const int wid = threadIdx.x >> 6, lane = threadIdx.x & 63;
    if (lane == 0) { ls[wid] = s; lc[wid] = c; }
    __syncthreads();
    if (threadIdx.x == 0) {
        const float    st = ls[0] + ls[1] + ls[2] + ls[3];
        const unsigned ct = lc[0] + lc[1] + lc[2] + lc[3];
        const unsigned n  = ct > 1u ? ct : 1u;
        out[0] = st / (float)n;
    }
}

extern "C" void kernel_launch(void* const* d_in, const int* in_sizes, int n_in,
                              void* d_out, int out_size, void* d_ws, size_t ws_size,
                              hipStream_t stream) {
    const float2* pos  = (const float2*)d_in[0];   // node_positions (8,512,2)
    // d_in[1] = adjacency: unused by the reference outputs
    const int*    esrc = (const int*)d_in[2];       // edge_index[0]
    const int*    edst = esrc + EDGES;              // edge_index[1]

    float*        out  = (float*)d_out;
    float*        bsum = (float*)d_ws;
    unsigned int* bcnt = (unsigned int*)((float*)d_ws + NBUCKET);

    // zero the reduction buckets (ws is poisoned before every launch)
    hipMemsetAsync(d_ws, 0, NBUCKET * 2 * sizeof(float), stream);

    const int nPairs = EDGES * EDGES;
    pair_kernel<<<nPairs / 256, 256, 0, stream>>>(pos, esrc, edst, out, bsum, bcnt);
    finalize_kernel<<<1, 256, 0, stream>>>(bsum, bcnt, out);
}

// Round 2
// 191.743 us; speedup vs baseline: 1.1209x; 1.1209x over previous
//
#include <hip/hip_runtime.h>

// SpatialNonIntersectionAxiom: B=8, N=512, E=4096.
// Outputs (flat f32): [0] = loss, [1 .. 1+E*E) = violation_mask (0/1),
// [1+E*E .. 1+2*E*E) = violation_scores (= pair_loss, masked -> lower tri == 0).

#define EDGES   4096
#define LOGE    12
#define EPS     0.001f
#define PROX    0.15f
#define NBUCKET 2048

// ---------------- per-edge precompute (E=4096 threads) ----------------
// rec1 = {a1x, a1y, d1x, d1y}
// rec2 = {midx, midy, half, dda(=d1.a1)}
// rec3 = {sq, bitcast(src), bitcast(dst), 0}
__global__ __launch_bounds__(256) void edge_pre(
    const float2* __restrict__ pos,
    const int*    __restrict__ esrc,
    const int*    __restrict__ edst,
    float4* __restrict__ rec1, float4* __restrict__ rec2, float4* __restrict__ rec3)
{
#pragma clang fp contract(off)
    const int e = blockIdx.x * 256 + threadIdx.x;
    const int s = esrc[e], d = edst[e];
    const float2 a1 = pos[s], a2 = pos[d];
    const float d1x = a2.x - a1.x, d1y = a2.y - a1.y;
    const float midx = (a1.x + a2.x) * 0.5f, midy = (a1.y + a2.y) * 0.5f;
    const float half = sqrtf(d1x * d1x + d1y * d1y) * 0.5f;
    const float sq   = fmaxf(d1x * d1x + d1y * d1y, 1e-12f);
    const float dda  = d1x * a1.x + d1y * a1.y;
    rec1[e] = make_float4(a1.x, a1.y, d1x, d1y);
    rec2[e] = make_float4(midx, midy, half, dda);
    rec3[e] = make_float4(sq, __int_as_float(s), __int_as_float(d), 0.0f);
}

// ---------------- pair kernel: one thread per (i,j) ----------------
__global__ __launch_bounds__(256) void pair_kernel(
    const float4* __restrict__ rec1, const float4* __restrict__ rec2,
    const float4* __restrict__ rec3,
    float*        __restrict__ out,
    float*        __restrict__ bsum,
    unsigned int* __restrict__ bcnt)
{
#pragma clang fp contract(off)
    const int bi    = blockIdx.x;
    const int i     = bi >> 4;              // 16 blocks of 256 cols per row
    const int jbase = (bi & 15) << 8;
    const int j     = jbase + threadIdx.x;
    const int k     = (i << LOGE) | j;

    float* __restrict__ o_mask  = out + 1;
    float* __restrict__ o_score = out + 1 + EDGES * EDGES;

    // whole block in lower-or-diagonal triangle -> both outputs are exactly 0
    if (jbase + 255 <= i) {
        o_mask[k]  = 0.0f;
        o_score[k] = 0.0f;
        return;
    }

    const float4 r1i = rec1[i], r2i = rec2[i], r3i = rec3[i];   // block-uniform
    const float4 r1j = rec1[j], r2j = rec2[j], r3j = rec3[j];   // coalesced

    // ---------- candidate mask (bitwise-identical to reference path) ----------
    const float dmx  = r2i.x - r2j.x, dmy = r2i.y - r2j.y;
    const float dist = sqrtf(dmx * dmx + dmy * dmy);
    const float reach = r2i.z + r2j.z + PROX;

    const int si = __float_as_int(r3i.y), di_ = __float_as_int(r3i.z);
    const int sj = __float_as_int(r3j.y), dj  = __float_as_int(r3j.z);
    const bool upper  = j > i;
    const bool sameb  = (si >> 9) == (sj >> 9);
    const bool shares = (si == sj) | (si == dj) | (di_ == sj) | (di_ == dj);
    const bool mask   = (dist < reach) & upper & sameb & (!shares);

    // ---------- segment-segment distance (reference op order, IEEE div) ----------
    const float sqi = r3i.x, sqj = r3j.x;
    const float b = r1i.z * r1j.z + r1i.w * r1j.w;
    const float c = r2i.w - (r1i.z * r1j.x + r1i.w * r1j.y);
    const float f = (r1i.x * r1j.z + r1i.y * r1j.w) - r2j.w;
    const float denom = fmaxf(sqi * sqj - b * b, 1e-12f);

    float s = (b * f - c * sqj) / denom;
    s = fminf(fmaxf(s, 0.0f), 1.0f);
    const float t = fminf(fmaxf((b * s + f) / sqj, 0.0f), 1.0f);
    s = fminf(fmaxf((b * t - c) / sqi, 0.0f), 1.0f);

    const float cax = r1i.x + s * r1i.z, cay = r1i.y + s * r1i.w;
    const float cbx = r1j.x + t * r1j.z, cby = r1j.y + t * r1j.w;
    const float dx = cax - cbx, dy = cay - cby;
    const float dmin = sqrtf(dx * dx + dy * dy);

    const float pl = fmaxf(EPS - dmin, 0.0f) * (mask ? 1.0f : 0.0f);

    o_mask[k]  = (mask && pl > 0.0f) ? 1.0f : 0.0f;
    o_score[k] = pl;

    // ---------- reduction: sum(pair_loss), count(mask) ----------
    float vsum = pl;
    int   vcnt = mask ? 1 : 0;
    #pragma unroll
    for (int off = 32; off > 0; off >>= 1) {
        vsum += __shfl_xor(vsum, off, 64);
        vcnt += __shfl_xor(vcnt, off, 64);
    }
    __shared__ float    ls[4];
    __shared__ unsigned lc[4];
    const int wid = threadIdx.x >> 6, lane = threadIdx.x & 63;
    if (lane == 0) { ls[wid] = vsum; lc[wid] = (unsigned)vcnt; }
    __syncthreads();
    if (threadIdx.x == 0) {
        const float    s4 = ls[0] + ls[1] + ls[2] + ls[3];
        const unsigned c4 = lc[0] + lc[1] + lc[2] + lc[3];
        if (s4 != 0.0f || c4 != 0u) {
            const int bk = blockIdx.x & (NBUCKET - 1);
            atomicAdd(&bsum[bk], s4);
            atomicAdd(&bcnt[bk], c4);
        }
    }
}

__global__ __launch_bounds__(256) void finalize_kernel(
    const float* __restrict__ bsum, const unsigned* __restrict__ bcnt,
    float* __restrict__ out)
{
    float    s = 0.0f;
    unsigned c = 0u;
    for (int b = threadIdx.x; b < NBUCKET; b += 256) { s += bsum[b]; c += bcnt[b]; }
    #pragma unroll
    for (int off = 32; off > 0; off >>= 1) {
        s += __shfl_xor(s, off, 64);
        c += (unsigned)__shfl_xor((int)c, off, 64);
    }
    __shared__ float    ls[4];
    __shared__ unsigned lc[4];
    const int wid = threadIdx.x >> 6, lane = threadIdx.x & 63;
    if (lane == 0) { ls[wid] = s; lc[wid] = c; }
    __syncthreads();
    if (threadIdx.x == 0) {
        const float    st = ls[0] + ls[1] + ls[2] + ls[3];
        const unsigned ct = lc[0] + lc[1] + lc[2] + lc[3];
        const unsigned n  = ct > 1u ? ct : 1u;
        out[0] = st / (float)n;
    }
}

extern "C" void kernel_launch(void* const* d_in, const int* in_sizes, int n_in,
                              void* d_out, int out_size, void* d_ws, size_t ws_size,
                              hipStream_t stream) {
    const float2* pos  = (const float2*)d_in[0];   // node_positions (8,512,2)
    // d_in[1] = adjacency: unused
    const int*    esrc = (const int*)d_in[2];       // edge_index[0]
    const int*    edst = esrc + EDGES;              // edge_index[1]

    float*        out  = (float*)d_out;
    float*        bsum = (float*)d_ws;
    unsigned int* bcnt = (unsigned int*)((float*)d_ws + NBUCKET);
    float4*       rec1 = (float4*)((char*)d_ws + NBUCKET * 8);          // 16 KB in
    float4*       rec2 = rec1 + EDGES;
    float4*       rec3 = rec2 + EDGES;

    hipMemsetAsync(d_ws, 0, NBUCKET * 2 * sizeof(float), stream);

    edge_pre<<<EDGES / 256, 256, 0, stream>>>(pos, esrc, edst, rec1, rec2, rec3);
    pair_kernel<<<(EDGES * EDGES) / 256, 256, 0, stream>>>(rec1, rec2, rec3, out, bsum, bcnt);
    finalize_kernel<<<1, 256, 0, stream>>>(bsum, bcnt, out);
}

// Round 3
// 188.281 us; speedup vs baseline: 1.1415x; 1.0184x over previous
//
#include <hip/hip_runtime.h>

// SpatialNonIntersectionAxiom: B=8, N=512, E=4096.
// Outputs (flat f32): [0] = loss, [1 .. 1+E*E) = violation_mask (0/1),
// [1+E*E .. 1+2*E*E) = violation_scores (= pair_loss; lower tri == 0).

#define EDGES   4096
#define LOGE    12
#define EPS     0.001f
#define PROX    0.15f
#define NBUCKET 2048

// ---------------- per-edge precompute (E=4096 threads) ----------------
// rec1 = {a1x, a1y, d1x, d1y}
// rec2 = {midx, midy, half, dda(=d1.a1)}
// rec3 = {sq, bitcast(src), bitcast(dst), 0}
__global__ __launch_bounds__(256) void edge_pre(
    const float2* __restrict__ pos,
    const int*    __restrict__ esrc,
    const int*    __restrict__ edst,
    float4* __restrict__ rec1, float4* __restrict__ rec2, float4* __restrict__ rec3)
{
#pragma clang fp contract(off)
    const int e = blockIdx.x * 256 + threadIdx.x;
    const int s = esrc[e], d = edst[e];
    const float2 a1 = pos[s], a2 = pos[d];
    const float d1x = a2.x - a1.x, d1y = a2.y - a1.y;
    const float midx = (a1.x + a2.x) * 0.5f, midy = (a1.y + a2.y) * 0.5f;
    const float half = sqrtf(d1x * d1x + d1y * d1y) * 0.5f;
    const float sq   = fmaxf(d1x * d1x + d1y * d1y, 1e-12f);
    const float dda  = d1x * a1.x + d1y * a1.y;
    rec1[e] = make_float4(a1.x, a1.y, d1x, d1y);
    rec2[e] = make_float4(midx, midy, half, dda);
    rec3[e] = make_float4(sq, __int_as_float(s), __int_as_float(d), 0.0f);
}

// per-pair math: bitwise-identical to the passing round-1/2 path
__device__ __forceinline__ void pair_math(
    const float4 r1i, const float4 r2i, const float4 r3i,
    const float4 r1j, const float4 r2j, const float4 r3j,
    const bool upper, float& pl, bool& mask)
{
#pragma clang fp contract(off)
    const float dmx  = r2i.x - r2j.x, dmy = r2i.y - r2j.y;
    const float dist = sqrtf(dmx * dmx + dmy * dmy);
    const float reach = r2i.z + r2j.z + PROX;

    const int si = __float_as_int(r3i.y), di_ = __float_as_int(r3i.z);
    const int sj = __float_as_int(r3j.y), dj  = __float_as_int(r3j.z);
    const bool sameb  = (si >> 9) == (sj >> 9);
    const bool shares = (si == sj) | (si == dj) | (di_ == sj) | (di_ == dj);
    mask = (dist < reach) & upper & sameb & (!shares);

    const float sqi = r3i.x, sqj = r3j.x;
    const float b = r1i.z * r1j.z + r1i.w * r1j.w;
    const float c = r2i.w - (r1i.z * r1j.x + r1i.w * r1j.y);
    const float f = (r1i.x * r1j.z + r1i.y * r1j.w) - r2j.w;
    const float denom = fmaxf(sqi * sqj - b * b, 1e-12f);

    float s = (b * f - c * sqj) / denom;
    s = fminf(fmaxf(s, 0.0f), 1.0f);
    const float t = fminf(fmaxf((b * s + f) / sqj, 0.0f), 1.0f);
    s = fminf(fmaxf((b * t - c) / sqi, 0.0f), 1.0f);

    const float cax = r1i.x + s * r1i.z, cay = r1i.y + s * r1i.w;
    const float cbx = r1j.x + t * r1j.z, cby = r1j.y + t * r1j.w;
    const float dx = cax - cbx, dy = cay - cby;
    const float dmin = sqrtf(dx * dx + dy * dy);

    pl = fmaxf(EPS - dmin, 0.0f) * (mask ? 1.0f : 0.0f);
}

// ---------------- pair kernel: 4 pairs per thread ----------------
// grid = (4, 4096): blockIdx.y = row i, blockIdx.x = 1024-col block.
__global__ __launch_bounds__(256) void pair_kernel(
    const float4* __restrict__ rec1, const float4* __restrict__ rec2,
    const float4* __restrict__ rec3,
    float*        __restrict__ out,
    float*        __restrict__ bsum,
    unsigned int* __restrict__ bcnt)
{
#pragma clang fp contract(off)
    const int i     = blockIdx.y;
    const int jbase = blockIdx.x << 10;
    const int j0    = jbase + (threadIdx.x << 2);
    const int k0    = (i << LOGE) | j0;

    float* __restrict__ o_mask  = out + 1;
    float* __restrict__ o_score = out + 1 + EDGES * EDGES;

    // whole block has j <= i -> outputs exactly 0 (mask includes j > i)
    if (jbase + 1023 <= i) {
        #pragma unroll
        for (int u = 0; u < 4; ++u) { o_mask[k0 + u] = 0.0f; o_score[k0 + u] = 0.0f; }
        return;
    }

    const float4 r1i = rec1[i], r2i = rec2[i], r3i = rec3[i];   // uniform -> SGPR

    float vsum = 0.0f;
    int   vcnt = 0;
    #pragma unroll
    for (int u = 0; u < 4; ++u) {
        const int j = j0 + u;
        float pl; bool mask;
        pair_math(r1i, r2i, r3i, rec1[j], rec2[j], rec3[j], j > i, pl, mask);
        o_mask[k0 + u]  = (mask && pl > 0.0f) ? 1.0f : 0.0f;
        o_score[k0 + u] = pl;
        vsum += pl;
        vcnt += mask ? 1 : 0;
    }

    // ---------- block reduction: sum(pair_loss), count(mask) ----------
    #pragma unroll
    for (int off = 32; off > 0; off >>= 1) {
        vsum += __shfl_xor(vsum, off, 64);
        vcnt += __shfl_xor(vcnt, off, 64);
    }
    __shared__ float    ls[4];
    __shared__ unsigned lc[4];
    const int wid = threadIdx.x >> 6, lane = threadIdx.x & 63;
    if (lane == 0) { ls[wid] = vsum; lc[wid] = (unsigned)vcnt; }
    __syncthreads();
    if (threadIdx.x == 0) {
        const float    s4 = ls[0] + ls[1] + ls[2] + ls[3];
        const unsigned c4 = lc[0] + lc[1] + lc[2] + lc[3];
        if (s4 != 0.0f || c4 != 0u) {
            const int bk = ((blockIdx.y << 2) | blockIdx.x) & (NBUCKET - 1);
            atomicAdd(&bsum[bk], s4);
            atomicAdd(&bcnt[bk], c4);
        }
    }
}

__global__ __launch_bounds__(256) void finalize_kernel(
    const float* __restrict__ bsum, const unsigned* __restrict__ bcnt,
    float* __restrict__ out)
{
    float    s = 0.0f;
    unsigned c = 0u;
    for (int b = threadIdx.x; b < NBUCKET; b += 256) { s += bsum[b]; c += bcnt[b]; }
    #pragma unroll
    for (int off = 32; off > 0; off >>= 1) {
        s += __shfl_xor(s, off, 64);
        c += (unsigned)__shfl_xor((int)c, off, 64);
    }
    __shared__ float    ls[4];
    __shared__ unsigned lc[4];
    const int wid = threadIdx.x >> 6, lane = threadIdx.x & 63;
    if (lane == 0) { ls[wid] = s; lc[wid] = c; }
    __syncthreads();
    if (threadIdx.x == 0) {
        const float    st = ls[0] + ls[1] + ls[2] + ls[3];
        const unsigned ct = lc[0] + lc[1] + lc[2] + lc[3];
        const unsigned n  = ct > 1u ? ct : 1u;
        out[0] = st / (float)n;
    }
}

extern "C" void kernel_launch(void* const* d_in, const int* in_sizes, int n_in,
                              void* d_out, int out_size, void* d_ws, size_t ws_size,
                              hipStream_t stream) {
    const float2* pos  = (const float2*)d_in[0];   // node_positions (8,512,2)
    // d_in[1] = adjacency: unused
    const int*    esrc = (const int*)d_in[2];       // edge_index[0]
    const int*    edst = esrc + EDGES;              // edge_index[1]

    float*        out  = (float*)d_out;
    float*        bsum = (float*)d_ws;
    unsigned int* bcnt = (unsigned int*)((float*)d_ws + NBUCKET);
    float4*       rec1 = (float4*)((char*)d_ws + NBUCKET * 8);
    float4*       rec2 = rec1 + EDGES;
    float4*       rec3 = rec2 + EDGES;

    hipMemsetAsync(d_ws, 0, NBUCKET * 2 * sizeof(float), stream);

    edge_pre<<<EDGES / 256, 256, 0, stream>>>(pos, esrc, edst, rec1, rec2, rec3);
    dim3 grid(4, EDGES);
    pair_kernel<<<grid, 256, 0, stream>>>(rec1, rec2, rec3, out, bsum, bcnt);
    finalize_kernel<<<1, 256, 0, stream>>>(bsum, bcnt, out);
}

// Round 4
// 181.777 us; speedup vs baseline: 1.1824x; 1.0358x over previous
//
#include <hip/hip_runtime.h>

// SpatialNonIntersectionAxiom: B=8, N=512, E=4096.
// Outputs (flat f32): [0] = loss, [1 .. 1+E*E) = violation_mask (0/1),
// [1+E*E .. 1+2*E*E) = violation_scores (= pair_loss; lower tri == 0).

#define EDGES   4096
#define LOGE    12
#define EPS     0.001f
#define PROX    0.15f
#define NBUCKET 2048
#define ITILE   8      // rows per block
#define JBLK    512    // cols per block (2 per thread, strided by 256)

// ---------------- per-edge precompute (E=4096 threads) ----------------
// rec1 = {a1x, a1y, d1x, d1y}
// rec2 = {midx, midy, half, dda(=d1.a1)}
// rec3 = {sq, bitcast(src), bitcast(dst), 0}
__global__ __launch_bounds__(256) void edge_pre(
    const float2* __restrict__ pos,
    const int*    __restrict__ esrc,
    const int*    __restrict__ edst,
    float4* __restrict__ rec1, float4* __restrict__ rec2, float4* __restrict__ rec3)
{
#pragma clang fp contract(off)
    const int e = blockIdx.x * 256 + threadIdx.x;
    const int s = esrc[e], d = edst[e];
    const float2 a1 = pos[s], a2 = pos[d];
    const float d1x = a2.x - a1.x, d1y = a2.y - a1.y;
    const float midx = (a1.x + a2.x) * 0.5f, midy = (a1.y + a2.y) * 0.5f;
    const float half = sqrtf(d1x * d1x + d1y * d1y) * 0.5f;
    const float sq   = fmaxf(d1x * d1x + d1y * d1y, 1e-12f);
    const float dda  = d1x * a1.x + d1y * a1.y;
    rec1[e] = make_float4(a1.x, a1.y, d1x, d1y);
    rec2[e] = make_float4(midx, midy, half, dda);
    rec3[e] = make_float4(sq, __int_as_float(s), __int_as_float(d), 0.0f);
}

// per-pair math: bitwise-identical to the passing round-1/2/3 path
__device__ __forceinline__ void pair_math(
    const float4 r1i, const float4 r2i, const float4 r3i,
    const float4 r1j, const float4 r2j, const float4 r3j,
    const bool upper, float& pl, bool& mask)
{
#pragma clang fp contract(off)
    const float dmx  = r2i.x - r2j.x, dmy = r2i.y - r2j.y;
    const float dist = sqrtf(dmx * dmx + dmy * dmy);
    const float reach = r2i.z + r2j.z + PROX;

    const int si = __float_as_int(r3i.y), di_ = __float_as_int(r3i.z);
    const int sj = __float_as_int(r3j.y), dj  = __float_as_int(r3j.z);
    const bool sameb  = (si >> 9) == (sj >> 9);
    const bool shares = (si == sj) | (si == dj) | (di_ == sj) | (di_ == dj);
    mask = (dist < reach) & upper & sameb & (!shares);

    const float sqi = r3i.x, sqj = r3j.x;
    const float b = r1i.z * r1j.z + r1i.w * r1j.w;
    const float c = r2i.w - (r1i.z * r1j.x + r1i.w * r1j.y);
    const float f = (r1i.x * r1j.z + r1i.y * r1j.w) - r2j.w;
    const float denom = fmaxf(sqi * sqj - b * b, 1e-12f);

    float s = (b * f - c * sqj) / denom;
    s = fminf(fmaxf(s, 0.0f), 1.0f);
    const float t = fminf(fmaxf((b * s + f) / sqj, 0.0f), 1.0f);
    s = fminf(fmaxf((b * t - c) / sqi, 0.0f), 1.0f);

    const float cax = r1i.x + s * r1i.z, cay = r1i.y + s * r1i.w;
    const float cbx = r1j.x + t * r1j.z, cby = r1j.y + t * r1j.w;
    const float dx = cax - cbx, dy = cay - cby;
    const float dmin = sqrtf(dx * dx + dy * dy);

    pl = fmaxf(EPS - dmin, 0.0f) * (mask ? 1.0f : 0.0f);
}

// ---------------- pair kernel: 8 rows x 512 cols per block ----------------
// grid = (8, 512): blockIdx.x = j-block (512 cols), blockIdx.y = i-block (8 rows).
// Each thread: j0 = jbase+tid, j1 = j0+256 (all loads/stores wave-coalesced),
// loops over 8 block-uniform rows -> j-records reused 8x from registers.
__global__ __launch_bounds__(256) void pair_kernel(
    const float4* __restrict__ rec1, const float4* __restrict__ rec2,
    const float4* __restrict__ rec3,
    float*        __restrict__ out,
    float*        __restrict__ bsum,
    unsigned int* __restrict__ bcnt)
{
#pragma clang fp contract(off)
    const int ibase = blockIdx.y * ITILE;
    const int jbase = blockIdx.x * JBLK;
    const int tid   = threadIdx.x;

    float* __restrict__ o_mask  = out + 1;
    float* __restrict__ o_score = out + 1 + EDGES * EDGES;

    // block fully in lower-or-diagonal triangle -> outputs exactly 0
    if (jbase + JBLK - 1 <= ibase) {
        #pragma unroll
        for (int ii = 0; ii < ITILE; ++ii) {
            const int row = (ibase + ii) << LOGE;
            o_mask [row + jbase + tid]       = 0.0f;
            o_score[row + jbase + tid]       = 0.0f;
            o_mask [row + jbase + 256 + tid] = 0.0f;
            o_score[row + jbase + 256 + tid] = 0.0f;
        }
        return;
    }

    const int j0 = jbase + tid;
    const int j1 = j0 + 256;
    const float4 r1j0 = rec1[j0], r2j0 = rec2[j0], r3j0 = rec3[j0];
    const float4 r1j1 = rec1[j1], r2j1 = rec2[j1], r3j1 = rec3[j1];

    float vsum = 0.0f;
    int   vcnt = 0;

    #pragma unroll 2
    for (int ii = 0; ii < ITILE; ++ii) {
        const int i = ibase + ii;                       // block-uniform
        const float4 r1i = rec1[i], r2i = rec2[i], r3i = rec3[i];

        float pl0, pl1; bool m0, m1;
        pair_math(r1i, r2i, r3i, r1j0, r2j0, r3j0, j0 > i, pl0, m0);
        pair_math(r1i, r2i, r3i, r1j1, r2j1, r3j1, j1 > i, pl1, m1);

        const int row = i << LOGE;
        o_mask [row + j0] = (m0 && pl0 > 0.0f) ? 1.0f : 0.0f;
        o_score[row + j0] = pl0;
        o_mask [row + j1] = (m1 && pl1 > 0.0f) ? 1.0f : 0.0f;
        o_score[row + j1] = pl1;

        vsum += pl0 + pl1;
        vcnt += (m0 ? 1 : 0) + (m1 ? 1 : 0);
    }

    // ---------- block reduction: sum(pair_loss), count(mask) ----------
    #pragma unroll
    for (int off = 32; off > 0; off >>= 1) {
        vsum += __shfl_xor(vsum, off, 64);
        vcnt += __shfl_xor(vcnt, off, 64);
    }
    __shared__ float    ls[4];
    __shared__ unsigned lc[4];
    const int wid = tid >> 6, lane = tid & 63;
    if (lane == 0) { ls[wid] = vsum; lc[wid] = (unsigned)vcnt; }
    __syncthreads();
    if (tid == 0) {
        const float    s4 = ls[0] + ls[1] + ls[2] + ls[3];
        const unsigned c4 = lc[0] + lc[1] + lc[2] + lc[3];
        if (s4 != 0.0f || c4 != 0u) {
            const int bk = (blockIdx.y * 8 + blockIdx.x) & (NBUCKET - 1);
            atomicAdd(&bsum[bk], s4);
            atomicAdd(&bcnt[bk], c4);
        }
    }
}

__global__ __launch_bounds__(256) void finalize_kernel(
    const float* __restrict__ bsum, const unsigned* __restrict__ bcnt,
    float* __restrict__ out)
{
    float    s = 0.0f;
    unsigned c = 0u;
    for (int b = threadIdx.x; b < NBUCKET; b += 256) { s += bsum[b]; c += bcnt[b]; }
    #pragma unroll
    for (int off = 32; off > 0; off >>= 1) {
        s += __shfl_xor(s, off, 64);
        c += (unsigned)__shfl_xor((int)c, off, 64);
    }
    __shared__ float    ls[4];
    __shared__ unsigned lc[4];
    const int wid = threadIdx.x >> 6, lane = threadIdx.x & 63;
    if (lane == 0) { ls[wid] = s; lc[wid] = c; }
    __syncthreads();
    if (threadIdx.x == 0) {
        const float    st = ls[0] + ls[1] + ls[2] + ls[3];
        const unsigned ct = lc[0] + lc[1] + lc[2] + lc[3];
        const unsigned n  = ct > 1u ? ct : 1u;
        out[0] = st / (float)n;
    }
}

extern "C" void kernel_launch(void* const* d_in, const int* in_sizes, int n_in,
                              void* d_out, int out_size, void* d_ws, size_t ws_size,
                              hipStream_t stream) {
    const float2* pos  = (const float2*)d_in[0];   // node_positions (8,512,2)
    // d_in[1] = adjacency: unused
    const int*    esrc = (const int*)d_in[2];       // edge_index[0]
    const int*    edst = esrc + EDGES;              // edge_index[1]

    float*        out  = (float*)d_out;
    float*        bsum = (float*)d_ws;
    unsigned int* bcnt = (unsigned int*)((float*)d_ws + NBUCKET);
    float4*       rec1 = (float4*)((char*)d_ws + NBUCKET * 8);
    float4*       rec2 = rec1 + EDGES;
    float4*       rec3 = rec2 + EDGES;

    hipMemsetAsync(d_ws, 0, NBUCKET * 2 * sizeof(float), stream);

    edge_pre<<<EDGES / 256, 256, 0, stream>>>(pos, esrc, edst, rec1, rec2, rec3);
    dim3 grid(EDGES / JBLK, EDGES / ITILE);   // (8, 512)
    pair_kernel<<<grid, 256, 0, stream>>>(rec1, rec2, rec3, out, bsum, bcnt);
    finalize_kernel<<<1, 256, 0, stream>>>(bsum, bcnt, out);
}

// Round 5
// 181.712 us; speedup vs baseline: 1.1828x; 1.0004x over previous
//
#include <hip/hip_runtime.h>

// SpatialNonIntersectionAxiom: B=8, N=512, E=4096.
// Outputs (flat f32): [0] = loss, [1 .. 1+E*E) = violation_mask (0/1),
// [1+E*E .. 1+2*E*E) = violation_scores (= pair_loss; lower tri == 0).

#define EDGES   4096
#define LOGE    12
#define EPS     0.001f
#define PROX    0.15f
#define NBUCKET 2048
#define ITILE   8      // rows per block
#define JBLK    512    // cols per block (2 per thread, strided by 256)

// ---------------- per-edge precompute (E=4096 threads) ----------------
// rec1 = {a1x, a1y, d1x, d1y}
// rec2 = {midx, midy, half, dda(=d1.a1)}
// rec3 = {sq, bitcast(src), bitcast(dst), 0}
__global__ __launch_bounds__(256) void edge_pre(
    const float2* __restrict__ pos,
    const int*    __restrict__ esrc,
    const int*    __restrict__ edst,
    float4* __restrict__ rec1, float4* __restrict__ rec2, float4* __restrict__ rec3)
{
#pragma clang fp contract(off)
    const int e = blockIdx.x * 256 + threadIdx.x;
    const int s = esrc[e], d = edst[e];
    const float2 a1 = pos[s], a2 = pos[d];
    const float d1x = a2.x - a1.x, d1y = a2.y - a1.y;
    const float midx = (a1.x + a2.x) * 0.5f, midy = (a1.y + a2.y) * 0.5f;
    const float half = sqrtf(d1x * d1x + d1y * d1y) * 0.5f;
    const float sq   = fmaxf(d1x * d1x + d1y * d1y, 1e-12f);
    const float dda  = d1x * a1.x + d1y * a1.y;
    rec1[e] = make_float4(a1.x, a1.y, d1x, d1y);
    rec2[e] = make_float4(midx, midy, half, dda);
    rec3[e] = make_float4(sq, __int_as_float(s), __int_as_float(d), 0.0f);
}

// per-pair math: bitwise-identical to the passing round-1..4 path
__device__ __forceinline__ void pair_math(
    const float4 r1i, const float4 r2i, const float4 r3i,
    const float4 r1j, const float4 r2j, const float4 r3j,
    const bool upper, float& pl, bool& mask)
{
#pragma clang fp contract(off)
    const float dmx  = r2i.x - r2j.x, dmy = r2i.y - r2j.y;
    const float dist = sqrtf(dmx * dmx + dmy * dmy);
    const float reach = r2i.z + r2j.z + PROX;

    const int si = __float_as_int(r3i.y), di_ = __float_as_int(r3i.z);
    const int sj = __float_as_int(r3j.y), dj  = __float_as_int(r3j.z);
    const bool sameb  = (si >> 9) == (sj >> 9);
    const bool shares = (si == sj) | (si == dj) | (di_ == sj) | (di_ == dj);
    mask = (dist < reach) & upper & sameb & (!shares);

    const float sqi = r3i.x, sqj = r3j.x;
    const float b = r1i.z * r1j.z + r1i.w * r1j.w;
    const float c = r2i.w - (r1i.z * r1j.x + r1i.w * r1j.y);
    const float f = (r1i.x * r1j.z + r1i.y * r1j.w) - r2j.w;
    const float denom = fmaxf(sqi * sqj - b * b, 1e-12f);

    float s = (b * f - c * sqj) / denom;
    s = fminf(fmaxf(s, 0.0f), 1.0f);
    const float t = fminf(fmaxf((b * s + f) / sqj, 0.0f), 1.0f);
    s = fminf(fmaxf((b * t - c) / sqi, 0.0f), 1.0f);

    const float cax = r1i.x + s * r1i.z, cay = r1i.y + s * r1i.w;
    const float cbx = r1j.x + t * r1j.z, cby = r1j.y + t * r1j.w;
    const float dx = cax - cbx, dy = cay - cby;
    const float dmin = sqrtf(dx * dx + dy * dy);

    pl = fmaxf(EPS - dmin, 0.0f) * (mask ? 1.0f : 0.0f);
}

// ---------------- pair kernel: 8 rows x 512 cols per block ----------------
// Compute into LDS (col shifted +1 so output quads are 16B-aligned), then
// write out with float4 stores: global offset 1 + row*4096 + jbase + 3 + 4q
// is a multiple of 4 elements -> aligned. 127 quads + 4 edge scalars per
// row per plane. Store instrs per thread: ~8.3 (was 32).
__global__ __launch_bounds__(256) void pair_kernel(
    const float4* __restrict__ rec1, const float4* __restrict__ rec2,
    const float4* __restrict__ rec3,
    float*        __restrict__ out,
    float*        __restrict__ bsum,
    unsigned int* __restrict__ bcnt)
{
#pragma clang fp contract(off)
    __shared__ float lds[2][ITILE][JBLK + 1];   // [plane][row][1+col], 32.8 KB

    const int ibase = blockIdx.y * ITILE;
    const int jbase = blockIdx.x * JBLK;
    const int tid   = threadIdx.x;

    float* __restrict__ o_mask  = out + 1;
    float* __restrict__ o_score = out + 1 + EDGES * EDGES;

    // block fully in lower-or-diagonal triangle -> outputs exactly 0
    if (jbase + JBLK - 1 <= ibase) {
        const float4 z4 = make_float4(0.0f, 0.0f, 0.0f, 0.0f);
        #pragma unroll
        for (int w = 0; w < 8; ++w) {
            const int qi = w * 256 + tid;           // [0, 2048)
            const int p  = qi >> 10;
            const int r  = (qi >> 7) & 7;
            const int q  = qi & 127;
            float* base = (p ? o_score : o_mask) + ((ibase + r) << LOGE) + jbase;
            if (q < 127) {
                *(float4*)(base + 3 + 4 * q) = z4;
            } else {
                base[0] = 0.0f; base[1] = 0.0f; base[2] = 0.0f; base[511] = 0.0f;
            }
        }
        return;
    }

    const int j0 = jbase + tid;
    const int j1 = j0 + 256;
    const float4 r1j0 = rec1[j0], r2j0 = rec2[j0], r3j0 = rec3[j0];
    const float4 r1j1 = rec1[j1], r2j1 = rec2[j1], r3j1 = rec3[j1];

    float vsum = 0.0f;
    int   vcnt = 0;

    #pragma unroll 2
    for (int ii = 0; ii < ITILE; ++ii) {
        const int i = ibase + ii;                       // block-uniform
        const float4 r1i = rec1[i], r2i = rec2[i], r3i = rec3[i];

        float pl0, pl1; bool m0, m1;
        pair_math(r1i, r2i, r3i, r1j0, r2j0, r3j0, j0 > i, pl0, m0);
        pair_math(r1i, r2i, r3i, r1j1, r2j1, r3j1, j1 > i, pl1, m1);

        lds[0][ii][1 + tid]       = (m0 && pl0 > 0.0f) ? 1.0f : 0.0f;
        lds[1][ii][1 + tid]       = pl0;
        lds[0][ii][1 + tid + 256] = (m1 && pl1 > 0.0f) ? 1.0f : 0.0f;
        lds[1][ii][1 + tid + 256] = pl1;

        vsum += pl0 + pl1;
        vcnt += (m0 ? 1 : 0) + (m1 ? 1 : 0);
    }

    // ---------- block reduction: sum(pair_loss), count(mask) ----------
    #pragma unroll
    for (int off = 32; off > 0; off >>= 1) {
        vsum += __shfl_xor(vsum, off, 64);
        vcnt += __shfl_xor(vcnt, off, 64);
    }
    __shared__ float    ls[4];
    __shared__ unsigned lc[4];
    const int wid = tid >> 6, lane = tid & 63;
    if (lane == 0) { ls[wid] = vsum; lc[wid] = (unsigned)vcnt; }
    __syncthreads();
    if (tid == 0) {
        const float    s4 = ls[0] + ls[1] + ls[2] + ls[3];
        const unsigned c4 = lc[0] + lc[1] + lc[2] + lc[3];
        if (s4 != 0.0f || c4 != 0u) {
            const int bk = (blockIdx.y * 8 + blockIdx.x) & (NBUCKET - 1);
            atomicAdd(&bsum[bk], s4);
            atomicAdd(&bcnt[bk], c4);
        }
    }

    // ---------- vectorized writeout from LDS ----------
    #pragma unroll
    for (int w = 0; w < 8; ++w) {
        const int qi = w * 256 + tid;               // [0, 2048)
        const int p  = qi >> 10;
        const int r  = (qi >> 7) & 7;
        const int q  = qi & 127;
        float* base = (p ? o_score : o_mask) + ((ibase + r) << LOGE) + jbase;
        if (q < 127) {
            const float4 v = *(const float4*)&lds[p][r][4 + 4 * q];   // 16B-aligned
            *(float4*)(base + 3 + 4 * q) = v;
        } else {
            base[0]   = lds[p][r][1];
            base[1]   = lds[p][r][2];
            base[2]   = lds[p][r][3];
            base[511] = lds[p][r][512];
        }
    }
}

__global__ __launch_bounds__(256) void finalize_kernel(
    const float* __restrict__ bsum, const unsigned* __restrict__ bcnt,
    float* __restrict__ out)
{
    float    s = 0.0f;
    unsigned c = 0u;
    for (int b = threadIdx.x; b < NBUCKET; b += 256) { s += bsum[b]; c += bcnt[b]; }
    #pragma unroll
    for (int off = 32; off > 0; off >>= 1) {
        s += __shfl_xor(s, off, 64);
        c += (unsigned)__shfl_xor((int)c, off, 64);
    }
    __shared__ float    ls[4];
    __shared__ unsigned lc[4];
    const int wid = threadIdx.x >> 6, lane = threadIdx.x & 63;
    if (lane == 0) { ls[wid] = s; lc[wid] = c; }
    __syncthreads();
    if (threadIdx.x == 0) {
        const float    st = ls[0] + ls[1] + ls[2] + ls[3];
        const unsigned ct = lc[0] + lc[1] + lc[2] + lc[3];
        const unsigned n  = ct > 1u ? ct : 1u;
        out[0] = st / (float)n;
    }
}

extern "C" void kernel_launch(void* const* d_in, const int* in_sizes, int n_in,
                              void* d_out, int out_size, void* d_ws, size_t ws_size,
                              hipStream_t stream) {
    const float2* pos  = (const float2*)d_in[0];   // node_positions (8,512,2)
    // d_in[1] = adjacency: unused
    const int*    esrc = (const int*)d_in[2];       // edge_index[0]
    const int*    edst = esrc + EDGES;              // edge_index[1]

    float*        out  = (float*)d_out;
    float*        bsum = (float*)d_ws;
    unsigned int* bcnt = (unsigned int*)((float*)d_ws + NBUCKET);
    float4*       rec1 = (float4*)((char*)d_ws + NBUCKET * 8);
    float4*       rec2 = rec1 + EDGES;
    float4*       rec3 = rec2 + EDGES;

    hipMemsetAsync(d_ws, 0, NBUCKET * 2 * sizeof(float), stream);

    edge_pre<<<EDGES / 256, 256, 0, stream>>>(pos, esrc, edst, rec1, rec2, rec3);
    dim3 grid(EDGES / JBLK, EDGES / ITILE);   // (8, 512)
    pair_kernel<<<grid, 256, 0, stream>>>(rec1, rec2, rec3, out, bsum, bcnt);
    finalize_kernel<<<1, 256, 0, stream>>>(bsum, bcnt, out);
}